// Round 5
// baseline (46.114 us; speedup 1.0000x reference)
//
#include <hip/hip_runtime.h>
#include <hip/hip_bf16.h>

// SConv2dAvg: stride-2 conv with per-output-pixel stochastic tap selection.
// B=32 C=128 H=W=64, O=256 kh=kw=3, oh=ow=32, PAD=1, STRIDE=2.
//
// Plan:
//  1) prep (fused): weight fp32 -> bf16 wpre[36][256][32] (K = tap*128+c,
//     K-step 32, 2-bit XOR swizzle baked), and input NCHW fp32 -> bf16 padded
//     NHWC tp[32][66][66][128] (zero halo -> no bounds checks in main loop).
//  2) sconv_mfma5: implicit GEMM, block 128o x 128pix, 4 waves of 64x64
//     (higher FLOP/LDS-byte than 8 waves of 64x32), K-step 32, 4 LDS buffers,
//     2-deep prefetch, 1 barrier/step, counted vmcnt (T3/T4), setprio (T5),
//     XCD-chunked block swizzle (T1).

typedef short bf16x8 __attribute__((ext_vector_type(8)));
typedef float f32x4  __attribute__((ext_vector_type(4)));

#define NSTEP 36
#define WPRE_BYTES (NSTEP * 256 * 32 * 2)           // 589824
#define TRANS_BYTES (32 * 66 * 66 * 128 * 2)        // 35684352
#define TOTAL_WS (WPRE_BYTES + TRANS_BYTES)

__device__ __forceinline__ unsigned short f2bf(float x) {
  unsigned u = __float_as_uint(x);
  return (unsigned short)((u + 0x7fffu + ((u >> 16) & 1u)) >> 16);
}
__device__ __forceinline__ unsigned pk2(float a, float b) {
  unsigned ua = __float_as_uint(a), ub = __float_as_uint(b);
  return ((ua + 0x7fffu + ((ua >> 16) & 1u)) >> 16) |
         ((ub + 0x7fffu + ((ub >> 16) & 1u)) & 0xffff0000u);
}
__device__ __forceinline__ bf16x8 ld_frag(const uint4* a) {
  union { uint4 u; bf16x8 s; } cv; cv.u = *a; return cv.s;
}
__device__ __forceinline__ void async16(const void* g, void* l) {
  __builtin_amdgcn_global_load_lds(
      (__attribute__((address_space(1))) void*)(void*)g,
      (__attribute__((address_space(3))) void*)l, 16, 0, 0);
}

// ---------------- fused pre-pass: transform + wprep ------------------------
// grid (102, 32): x < 66 -> padded-NHWC transform of (row hp=x, batch y);
//                 x >= 66 -> wprep K-slice s = x-66, o-block = y (8 o's).
__global__ __launch_bounds__(256) void prep(const float* __restrict__ in,
                                            const float* __restrict__ w,
                                            unsigned short* __restrict__ tp,
                                            unsigned short* __restrict__ wpre) {
  const int tid = threadIdx.x;
  if (blockIdx.x >= 66) {   // ---- weight prep: wpre[s][o][32], swizzle baked
    const int s    = blockIdx.x - 66;       // 0..35
    const int o    = (blockIdx.y << 3) + (tid >> 5);
    const int k_in = tid & 31;
    const int kg   = (s << 5) + (((k_in >> 3) ^ ((o >> 1) & 3)) << 3) + (k_in & 7);
    const int tap  = kg >> 7;
    const int c    = kg & 127;
    const int di   = (tap >= 6) ? 2 : ((tap >= 3) ? 1 : 0);
    const int dj   = tap - di * 3;
    wpre[(s << 13) + (o << 5) + k_in] = f2bf(w[(o * 128 + c) * 9 + di * 3 + dj]);
    return;
  }
  // ---- input transform ----
  __shared__ float lds[128 * 65];
  const int hp = blockIdx.x;   // 0..65 padded row
  const int b  = blockIdx.y;
  uint4* rowp = (uint4*)(tp + (size_t)(b * 66 + hp) * 66 * 128);
  uint4 z; z.x = z.y = z.z = z.w = 0u;
  if (hp == 0 || hp == 65) {                 // zero border rows
    for (int s = tid; s < 1056; s += 256) rowp[s] = z;
    return;
  }
  const int h = hp - 1;
  const float* src = in + ((size_t)b << 19) + (h << 6);
  const int ww4 = (tid & 15) << 2;
  const int c0  = tid >> 4;
#pragma unroll
  for (int pass = 0; pass < 8; ++pass) {
    int c = (pass << 4) + c0;
    float4 v = *(const float4*)(src + ((size_t)c << 12) + ww4);  // coalesced
    float* lp = lds + c * 65 + ww4;
    lp[0] = v.x; lp[1] = v.y; lp[2] = v.z; lp[3] = v.w;
  }
  __syncthreads();
  for (int s = tid; s < 1056; s += 256) {
    if (s < 16 || s >= 1040) { rowp[s] = z; continue; }   // zero border cols
    int idx = s - 16;
    int wq = idx >> 4, c8 = idx & 15;
    const float* lp = lds + (c8 << 3) * 65 + wq;
    uint4 d;
    d.x = pk2(lp[0],   lp[65]);
    d.y = pk2(lp[130], lp[195]);
    d.z = pk2(lp[260], lp[325]);
    d.w = pk2(lp[390], lp[455]);
    rowp[s] = d;
  }
}

// ----------------------------- main kernel ---------------------------------
// grid 512 (XCD-chunked), 256 threads / 4 waves, each wave 64o x 64pix.
// K-step 32, 4 LDS buffers (A 8KB + B 8KB each), 2-deep prefetch,
// one barrier per step, counted vmcnt (never 0 in steady loop).
__global__ __launch_bounds__(256, 2) void sconv_mfma5(
    const unsigned short* __restrict__ tp,   // [32][66][66][128] bf16 padded
    const unsigned short* __restrict__ wpre, // [36][256][32] bf16 pre-swizzled
    const float* __restrict__ bias,
    const int* __restrict__ selh,            // [32][32]
    const int* __restrict__ selw,            // [32][32]
    float* __restrict__ out)                 // [32][256][32][32]
{
  __shared__ uint4 Alds[4][512];   // patches [pix(128)][4 chunks], 8KB/buf
  __shared__ uint4 Blds[4][512];   // weights [o_local(128)][4 chunks], swz baked
  __shared__ float bias_s[128];

  const int tid = threadIdx.x;
  // XCD-chunked swizzle (T1): 512 = 8 XCDs x 64 consecutive logical tiles
  const int d0    = blockIdx.x;
  const int blk   = ((d0 & 7) << 6) + (d0 >> 3);
  const int b     = blk >> 4;
  const int y0    = ((blk >> 1) & 7) << 2;
  const int ohalf = blk & 1;

  if (tid < 128) bias_s[tid] = bias[(ohalf << 7) + tid];

  const int wv = tid >> 6, ln = tid & 63;

  // ---- gather role: wave wv stages pixels [wv*32, wv*32+32) in 2 calls;
  // lane ln covers pixel p = wv*32 + r*16 + (ln>>2), chunk c4 = ln&3.
  size_t asrc0, asrc1;             // per-lane source offset at tap(0,0), k=0
  {
    const int c4 = ln & 3;
#pragma unroll
    for (int r = 0; r < 2; ++r) {
      const int p  = (wv << 5) + (r << 4) + (ln >> 2);
      const int py = y0 + (p >> 5);
      const int px = p & 31;
      const int addr = (b * 66 + 2 * py + selh[(py << 5) | px]) * 66
                     + 2 * px + selw[(py << 5) | px];
      const int u = c4 ^ ((p >> 1) & 3);   // 2-bit XOR swizzle on source chunk
      const size_t v = ((size_t)addr << 8) + (u << 4);
      if (r == 0) asrc0 = v; else asrc1 = v;
    }
  }
  const char* tbase = (const char*)tp;
  // B source: per-lane linear (swizzle baked in wpre)
  const char* wB = (const char*)wpre + (ohalf << 13) + ((wv << 1) << 10) + (ln << 4);

  // ---- MFMA role: wave (wo, wp) owns 64o x 64pix
  const int wo = wv & 1, wp = wv >> 1;
  const int lo = ln & 15, hi = ln >> 4;

  f32x4 acc[4][4] = {};             // [o-frag][pix-frag]

#define STAGE(BUF, KK)                                                        \
  do {                                                                        \
    const int tap_ = (KK) >> 2;                                               \
    const int di_  = (tap_ >= 6) ? 2 : ((tap_ >= 3) ? 1 : 0);                 \
    const int dj_  = tap_ - 3 * di_;                                          \
    const int toff_ = ((di_ * 66 + dj_) << 8) + (((KK) & 3) << 6);            \
    async16(tbase + asrc0 + toff_, &Alds[BUF][(wv << 1) << 6]);               \
    async16(tbase + asrc1 + toff_, &Alds[BUF][((wv << 1) + 1) << 6]);         \
    async16(wB + ((KK) << 14),        &Blds[BUF][(wv << 1) << 6]);            \
    async16(wB + ((KK) << 14) + 1024, &Blds[BUF][((wv << 1) + 1) << 6]);      \
  } while (0)

#define DO_MMA(BUF)                                                           \
  do {                                                                        \
    const uint4* A_ = &Alds[BUF][0];                                          \
    const uint4* B_ = &Blds[BUF][0];                                          \
    bf16x8 FW[4], FP[4];                                                      \
    _Pragma("unroll")                                                         \
    for (int f = 0; f < 4; ++f) {                                             \
      const int orow = (wo << 6) + (f << 4) + lo;                             \
      FW[f] = ld_frag(B_ + (orow << 2) + (hi ^ ((orow >> 1) & 3)));           \
    }                                                                         \
    _Pragma("unroll")                                                         \
    for (int f = 0; f < 4; ++f) {                                             \
      const int prow = (wp << 6) + (f << 4) + lo;                             \
      FP[f] = ld_frag(A_ + (prow << 2) + (hi ^ ((prow >> 1) & 3)));           \
    }                                                                         \
    __builtin_amdgcn_s_setprio(1);                                            \
    _Pragma("unroll")                                                         \
    for (int fo = 0; fo < 4; ++fo)                                            \
      _Pragma("unroll")                                                       \
      for (int fp = 0; fp < 4; ++fp)                                          \
        acc[fo][fp] = __builtin_amdgcn_mfma_f32_16x16x32_bf16(                \
            FW[fo], FP[fp], acc[fo][fp], 0, 0, 0);                            \
    __builtin_amdgcn_s_setprio(0);                                            \
  } while (0)

  STAGE(0, 0);                      // prologue: 2 steps (8 loads) in flight
  STAGE(1, 1);

#pragma unroll 4
  for (int kk = 0; kk < NSTEP - 2; ++kk) {
    STAGE((kk + 2) & 3, kk + 2);                         // 2-deep prefetch
    asm volatile("s_waitcnt vmcnt(8)" ::: "memory");     // step-kk loads landed
    __builtin_amdgcn_s_barrier();
    asm volatile("" ::: "memory");
    DO_MMA(kk & 3);
    asm volatile("s_waitcnt lgkmcnt(0)" ::: "memory");   // reads drained before
  }                                                      // next barrier

  asm volatile("s_waitcnt vmcnt(4)" ::: "memory");       // step 34
  __builtin_amdgcn_s_barrier();
  asm volatile("" ::: "memory");
  DO_MMA(2);
  asm volatile("s_waitcnt lgkmcnt(0)" ::: "memory");

  asm volatile("s_waitcnt vmcnt(0)" ::: "memory");       // step 35
  __builtin_amdgcn_s_barrier();
  asm volatile("" ::: "memory");
  DO_MMA(3);
#undef STAGE
#undef DO_MMA

  // ---- epilogue: D row = o (hi*4+j), col = pix (lo); +bias
  float* ob = out + ((size_t)b << 18) + ((size_t)ohalf << 17) + (y0 << 5);
#pragma unroll
  for (int fo = 0; fo < 4; ++fo) {
    const int obase = (wo << 6) + (fo << 4) + (hi << 2);
#pragma unroll
    for (int fp = 0; fp < 4; ++fp) {
      const int pix = (wp << 6) + (fp << 4) + lo;
#pragma unroll
      for (int j = 0; j < 4; ++j) {
        const int o = obase + j;
        ob[((size_t)o << 10) + pix] = acc[fo][fp][j] + bias_s[o];
      }
    }
  }
}

// ------------------- exact fp32 fallback (ws too small) --------------------
__global__ __launch_bounds__(256) void sconv_naive(
    const float* __restrict__ in, const float* __restrict__ w,
    const float* __restrict__ bias, const int* __restrict__ selh,
    const int* __restrict__ selw, float* __restrict__ out) {
  int idx = (blockIdx.x << 8) + threadIdx.x;
  if (idx >= 32 * 256 * 32 * 32) return;
  int x = idx & 31, y = (idx >> 5) & 31, o = (idx >> 10) & 255, b = idx >> 18;
  int rh0 = 2 * y + selh[(y << 5) | x] - 1;
  int rw0 = 2 * x + selw[(y << 5) | x] - 1;
  const float* inb = in + ((size_t)b << 19);
  const float* wo_ = w + o * 1152;
  float acc = bias[o];
  for (int c = 0; c < 128; ++c)
    for (int i = 0; i < 3; ++i) {
      int rh = rh0 + i;
      if (rh < 0 || rh >= 64) continue;
      for (int j = 0; j < 3; ++j) {
        int rw = rw0 + j;
        if (rw < 0 || rw >= 64) continue;
        acc += inb[(c << 12) + (rh << 6) + rw] * wo_[c * 9 + i * 3 + j];
      }
    }
  out[idx] = acc;
}

extern "C" void kernel_launch(void* const* d_in, const int* in_sizes, int n_in,
                              void* d_out, int out_size, void* d_ws, size_t ws_size,
                              hipStream_t stream) {
  const float* in   = (const float*)d_in[0];
  const float* w    = (const float*)d_in[1];
  const float* bias = (const float*)d_in[2];
  const int*   selh = (const int*)d_in[3];
  const int*   selw = (const int*)d_in[4];
  float* out = (float*)d_out;

  if (ws_size >= (size_t)TOTAL_WS) {
    unsigned short* wpre = (unsigned short*)d_ws;
    unsigned short* tp   = (unsigned short*)((char*)d_ws + WPRE_BYTES);
    prep<<<dim3(102, 32), dim3(256), 0, stream>>>(in, w, tp, wpre);
    sconv_mfma5<<<dim3(512), dim3(256), 0, stream>>>(tp, wpre, bias, selh, selw, out);
  } else {
    sconv_naive<<<dim3(32768), dim3(256), 0, stream>>>(in, w, bias, selh, selw, out);
  }
}